// Round 1
// baseline (551.258 us; speedup 1.0000x reference)
//
#include <hip/hip_runtime.h>
#include <cmath>

#define TOKENS 16384
#define DM     4096
#define NEXP   64

// ---------------- Kernel A: logits[t][e] = sum_k x[t][k] * wg[e][k] ----------
// Block tile: 32 tokens x 64 experts, K chunked by 64 staged transposed in LDS.
// 256 threads: thread = (e4 in [0,16)) + 16*(t2 in [0,16)); per-thread 4e x 2t.
#define KC  64
#define BT  32
#define WS_ 68   // wgT row stride (floats): 68*4=272 B, 16B-aligned rows
#define XS_ 36   // xT  row stride (floats): 36*4=144 B, 8B-aligned rows

__global__ __launch_bounds__(256, 2)
void logits_kernel(const float* __restrict__ x, const float* __restrict__ wg,
                   float* __restrict__ logits)
{
    __shared__ float wgT[KC * WS_];
    __shared__ float xT [KC * XS_];

    const int tid = threadIdx.x;
    const int t0  = blockIdx.x * BT;
    const int e4  = (tid & 15) << 2;   // expert base (0..60)
    const int t2  = (tid >> 4) << 1;   // token base within tile (0..30)

    float a00=0.f,a01=0.f,a02=0.f,a03=0.f;
    float a10=0.f,a11=0.f,a12=0.f,a13=0.f;

    for (int k0 = 0; k0 < DM; k0 += KC) {
        __syncthreads();
        // stage x tile (32 tok x 64 k): coalesced float4 reads, transposed LDS write
        #pragma unroll
        for (int j = 0; j < 2; ++j) {
            const int f4  = tid + 256*j;
            const int row = f4 >> 4;          // token 0..31
            const int col = (f4 & 15) << 2;   // k offset 0..60
            const float4 v = *(const float4*)(x + (size_t)(t0 + row)*DM + k0 + col);
            xT[(col+0)*XS_ + row] = v.x;
            xT[(col+1)*XS_ + row] = v.y;
            xT[(col+2)*XS_ + row] = v.z;
            xT[(col+3)*XS_ + row] = v.w;
        }
        // stage wg tile (64 exp x 64 k)
        #pragma unroll
        for (int j = 0; j < 4; ++j) {
            const int f4  = tid + 256*j;
            const int e   = f4 >> 4;          // expert 0..63
            const int col = (f4 & 15) << 2;
            const float4 v = *(const float4*)(wg + (size_t)e*DM + k0 + col);
            wgT[(col+0)*WS_ + e] = v.x;
            wgT[(col+1)*WS_ + e] = v.y;
            wgT[(col+2)*WS_ + e] = v.z;
            wgT[(col+3)*WS_ + e] = v.w;
        }
        __syncthreads();
        #pragma unroll 4
        for (int k = 0; k < KC; ++k) {
            const float4 wv = *(const float4*)&wgT[k*WS_ + e4];
            const float2 xv = *(const float2*)&xT [k*XS_ + t2];
            a00 += xv.x*wv.x; a01 += xv.x*wv.y; a02 += xv.x*wv.z; a03 += xv.x*wv.w;
            a10 += xv.y*wv.x; a11 += xv.y*wv.y; a12 += xv.y*wv.z; a13 += xv.y*wv.w;
        }
    }

    float* o0 = logits + (size_t)(t0 + t2)*NEXP + e4;
    o0[0]=a00; o0[1]=a01; o0[2]=a02; o0[3]=a03;
    float* o1 = o0 + NEXP;
    o1[0]=a10; o1[1]=a11; o1[2]=a12; o1[3]=a13;
}

// ---------------- Kernel B: softmax + top-2 + per-block partial reductions ---
// 256 blocks x 256 threads (4 waves). One wave per token (lane = expert),
// 16 tokens per wave. Partials: p_imp[block][64], p_cnt[block][64].
__global__ __launch_bounds__(256)
void gate_kernel(const float* __restrict__ logits, float* __restrict__ out,
                 float* __restrict__ p_imp, float* __restrict__ p_cnt)
{
    const int lane = threadIdx.x & 63;
    const int wave = threadIdx.x >> 6;
    const int blk  = blockIdx.x;

    float imp_acc = 0.f;
    float cnt_acc = 0.f;

    for (int i = 0; i < 16; ++i) {
        const int t = blk*64 + wave*16 + i;
        const float v = logits[(size_t)t*NEXP + lane];

        // softmax (over 64 lanes)
        float m = v;
        #pragma unroll
        for (int off = 32; off; off >>= 1) m = fmaxf(m, __shfl_xor(m, off));
        const float p = expf(v - m);
        float s = p;
        #pragma unroll
        for (int off = 32; off; off >>= 1) s += __shfl_xor(s, off);
        const float prob = p / s;

        // top-1 (argmax; ties -> lower index, matching lax.top_k)
        float bv = prob; int bi = lane;
        #pragma unroll
        for (int off = 32; off; off >>= 1) {
            const float ov = __shfl_xor(bv, off);
            const int   oi = __shfl_xor(bi, off);
            if (ov > bv || (ov == bv && oi < bi)) { bv = ov; bi = oi; }
        }
        // top-2: mask out winner, reduce again
        float cv = (lane == bi) ? -1.0f : prob; int ci = lane;
        #pragma unroll
        for (int off = 32; off; off >>= 1) {
            const float ov = __shfl_xor(cv, off);
            const int   oi = __shfl_xor(ci, off);
            if (ov > cv || (ov == cv && oi < ci)) { cv = ov; ci = oi; }
        }

        if (lane == 0) {
            out[2*t]                = (float)bi;
            out[2*t + 1]            = (float)ci;
            out[2*TOKENS + 2*t]     = bv;
            out[2*TOKENS + 2*t + 1] = cv;
        }
        imp_acc += prob;
        cnt_acc += (lane == bi) ? 1.0f : 0.0f;
    }

    __shared__ float red[4][NEXP];
    red[wave][lane] = imp_acc;
    __syncthreads();
    if (threadIdx.x < 64) {
        p_imp[blk*NEXP + threadIdx.x] =
            red[0][threadIdx.x] + red[1][threadIdx.x] +
            red[2][threadIdx.x] + red[3][threadIdx.x];
    }
    __syncthreads();
    red[wave][lane] = cnt_acc;
    __syncthreads();
    if (threadIdx.x < 64) {
        p_cnt[blk*NEXP + threadIdx.x] =
            red[0][threadIdx.x] + red[1][threadIdx.x] +
            red[2][threadIdx.x] + red[3][threadIdx.x];
    }
}

// ---------------- Kernel C: aux = E * sum_e importance_e * load_e -----------
__global__ __launch_bounds__(256)
void aux_kernel(const float* __restrict__ p_imp, const float* __restrict__ p_cnt,
                float* __restrict__ out)
{
    __shared__ float s_imp[256];
    __shared__ float s_cnt[256];
    const int tid = threadIdx.x;
    const int e = tid & 63;
    const int c = tid >> 6;           // 4 chunks of 64 blocks
    float si = 0.f, sc = 0.f;
    for (int b = c*64; b < c*64 + 64; ++b) {
        si += p_imp[b*NEXP + e];
        sc += p_cnt[b*NEXP + e];
    }
    s_imp[tid] = si; s_cnt[tid] = sc;
    __syncthreads();
    if (tid < 64) {
        const float imp = s_imp[tid] + s_imp[64+tid] + s_imp[128+tid] + s_imp[192+tid];
        const float cnt = s_cnt[tid] + s_cnt[64+tid] + s_cnt[128+tid] + s_cnt[192+tid];
        float prod = imp * cnt;
        #pragma unroll
        for (int off = 32; off; off >>= 1) prod += __shfl_xor(prod, off);
        if (tid == 0) {
            // aux = E * sum( (imp_sum/S) * (cnt/S) )
            out[4*TOKENS] = (float)NEXP * prod / ((float)TOKENS * (float)TOKENS);
        }
    }
}

extern "C" void kernel_launch(void* const* d_in, const int* in_sizes, int n_in,
                              void* d_out, int out_size, void* d_ws, size_t ws_size,
                              hipStream_t stream) {
    const float* x  = (const float*)d_in[0];
    const float* wg = (const float*)d_in[1];
    // d_in[2] is k (==2), fixed by the problem.
    float* out = (float*)d_out;

    float* logits = (float*)d_ws;                       // 16384*64 floats = 4 MB
    float* p_imp  = logits + (size_t)TOKENS*NEXP;       // 256*64 floats
    float* p_cnt  = p_imp + 256*NEXP;                   // 256*64 floats

    logits_kernel<<<TOKENS/BT, 256, 0, stream>>>(x, wg, logits);
    gate_kernel<<<TOKENS/64, 256, 0, stream>>>(logits, out, p_imp, p_cnt);
    aux_kernel<<<1, 256, 0, stream>>>(p_imp, p_cnt, out);
}